// Round 5
// baseline (52.271 us; speedup 1.0000x reference)
//
#include <hip/hip_runtime.h>
#include <math.h>

// Problem constants (from reference):
constexpr int Bn = 1024;
constexpr int S  = 512;
constexpr int H  = 768;
constexpr int D1 = 128;
constexpr int HV = H / 4;     // 192 float4 per feature row

constexpr int E  = 8;         // examples per head block
constexpr int NC = 8;         // d-chunks
constexpr int DC = (2 * H) / NC;  // 192 rows per chunk

// ws layout (floats):
//   cls [Bn][768]      — CLS features
//   gp  [2][Bn][768]   — span-mean partials (even/odd rows), pre-scaled by 1/len
//   P   [NC][Bn][D1]   — per-chunk partial h dots

// Kernel 1 (identical to round-2 measured best): ragged span mean-pool,
// 2 blocks/example (even/odd rows); 4 independent loads in flight/wave.
__global__ __launch_bounds__(192) void pool_partial(
    const float* __restrict__ feat, const int* __restrict__ start,
    const int* __restrict__ endp, float* __restrict__ cls,
    float* __restrict__ gp) {
  const int b = blockIdx.x >> 1;
  const int p = blockIdx.x & 1;
  const int t = threadIdx.x;  // one float4 column
  const float4* base = reinterpret_cast<const float4*>(feat) + (size_t)b * (S * HV);

  if (p == 0) {
    reinterpret_cast<float4*>(cls)[(size_t)b * HV + t] = base[t];  // CLS row
  }

  const int s0 = start[b];
  const int s1 = endp[b];
  float4 a0{0,0,0,0}, a1{0,0,0,0}, a2{0,0,0,0}, a3{0,0,0,0};
  int s = s0 + p;
  for (; s + 6 < s1; s += 8) {
    float4 v0 = base[(size_t)(s    ) * HV + t];
    float4 v1 = base[(size_t)(s + 2) * HV + t];
    float4 v2 = base[(size_t)(s + 4) * HV + t];
    float4 v3 = base[(size_t)(s + 6) * HV + t];
    a0.x += v0.x; a0.y += v0.y; a0.z += v0.z; a0.w += v0.w;
    a1.x += v1.x; a1.y += v1.y; a1.z += v1.z; a1.w += v1.w;
    a2.x += v2.x; a2.y += v2.y; a2.z += v2.z; a2.w += v2.w;
    a3.x += v3.x; a3.y += v3.y; a3.z += v3.z; a3.w += v3.w;
  }
  for (; s < s1; s += 2) {
    float4 v = base[(size_t)s * HV + t];
    a0.x += v.x; a0.y += v.y; a0.z += v.z; a0.w += v.w;
  }
  const float inv = 1.0f / (float)(s1 - s0);
  float4 r;
  r.x = ((a0.x + a1.x) + (a2.x + a3.x)) * inv;
  r.y = ((a0.y + a1.y) + (a2.y + a3.y)) * inv;
  r.z = ((a0.z + a1.z) + (a2.z + a3.z)) * inv;
  r.w = ((a0.w + a1.w) + (a2.w + a3.w)) * inv;
  reinterpret_cast<float4*>(gp)[((size_t)p * Bn + b) * HV + t] = r;
}

// Kernel 2: partial W1 dots, register-blocked.
// Block = 8 examples x 192-row d-chunk; 256 thr; grid 1024 -> 16 waves/CU.
// Lane = (kq = l&31 -> k-quad, half = l>>5); example e = wave*2 + half.
// Per 4-d group: 4 coalesced float4 W1 loads (L2) + ONE ds_read_b128 of g
// feeding 16 FMAs -> LDS pipe off the critical path.
__global__ __launch_bounds__(256) void head_partial(
    const float* __restrict__ cls, const float* __restrict__ gp,
    const float* __restrict__ W1, float* __restrict__ P) {
  __shared__ float g[E][DC];   // 6 KB

  const int t  = threadIdx.x;
  const int c  = blockIdx.x & (NC - 1);
  const int eg = blockIdx.x / NC;
  const int e0 = eg * E;
  const int d0 = c * DC;

  // Stage this chunk of g for 8 examples.
  constexpr int JV = DC / 4;   // 48 float4 per example-chunk
  if (d0 < H) {
    for (int i = t; i < E * JV; i += 256) {
      const int e = i / JV, j = i % JV;
      float4 v = reinterpret_cast<const float4*>(cls + (size_t)(e0 + e) * H + d0)[j];
      reinterpret_cast<float4*>(&g[e][0])[j] = v;
    }
  } else {
    const int dd0 = d0 - H;
    for (int i = t; i < E * JV; i += 256) {
      const int e = i / JV, j = i % JV;
      const float* b0 = gp + (size_t)(e0 + e) * H + dd0;
      float4 u0 = reinterpret_cast<const float4*>(b0)[j];
      float4 u1 = reinterpret_cast<const float4*>(b0 + (size_t)Bn * H)[j];
      float4 v;
      v.x = u0.x + u1.x; v.y = u0.y + u1.y;
      v.z = u0.z + u1.z; v.w = u0.w + u1.w;
      reinterpret_cast<float4*>(&g[e][0])[j] = v;
    }
  }
  __syncthreads();

  const int l    = t & 63;
  const int wv   = t >> 6;
  const int half = l >> 5;
  const int kq   = l & 31;          // k-quad: k0 = kq*4
  const int e    = wv * 2 + half;   // 0..7

  const float4* Wv = reinterpret_cast<const float4*>(W1 + (size_t)d0 * D1) + kq;
  float4 acc = {0.f, 0.f, 0.f, 0.f};
  #pragma unroll 4
  for (int dd = 0; dd < DC; dd += 4) {
    float4 w0 = Wv[(size_t)(dd + 0) * 32];
    float4 w1 = Wv[(size_t)(dd + 1) * 32];
    float4 w2 = Wv[(size_t)(dd + 2) * 32];
    float4 w3 = Wv[(size_t)(dd + 3) * 32];
    float4 gv = *reinterpret_cast<const float4*>(&g[e][dd]);
    acc.x += gv.x * w0.x + gv.y * w1.x + gv.z * w2.x + gv.w * w3.x;
    acc.y += gv.x * w0.y + gv.y * w1.y + gv.z * w2.y + gv.w * w3.y;
    acc.z += gv.x * w0.z + gv.y * w1.z + gv.z * w2.z + gv.w * w3.z;
    acc.w += gv.x * w0.w + gv.y * w1.w + gv.z * w2.w + gv.w * w3.w;
  }
  reinterpret_cast<float4*>(P + ((size_t)c * Bn + (e0 + e)) * D1)[kq] = acc;
}

// Kernel 3: combine chunks, relu, dot W2, sigmoid. One wave per example.
__global__ __launch_bounds__(256) void finalize(
    const float* __restrict__ P, const float* __restrict__ b1,
    const float* __restrict__ W2, const float* __restrict__ b2,
    float* __restrict__ out) {
  const int t = threadIdx.x;
  const int w = t >> 6, l = t & 63;
  const int e = blockIdx.x * 4 + w;
  const int k0 = l, k1 = l + 64;
  float h0 = b1[k0], h1 = b1[k1];
  #pragma unroll
  for (int c = 0; c < NC; ++c) {
    h0 += P[((size_t)c * Bn + e) * D1 + k0];
    h1 += P[((size_t)c * Bn + e) * D1 + k1];
  }
  h0 = fmaxf(h0, 0.f); h1 = fmaxf(h1, 0.f);
  float v = h0 * W2[k0] + h1 * W2[k1];
  #pragma unroll
  for (int off = 32; off > 0; off >>= 1) v += __shfl_down(v, off);
  if (l == 0) out[e] = 1.0f / (1.0f + expf(-(v + b2[0])));
}

extern "C" void kernel_launch(void* const* d_in, const int* in_sizes, int n_in,
                              void* d_out, int out_size, void* d_ws, size_t ws_size,
                              hipStream_t stream) {
  const float* feat = (const float*)d_in[0];   // [B,S,H] fp32
  const int* start  = (const int*)d_in[1];     // [B]
  const int* endp   = (const int*)d_in[2];     // [B]
  const float* W1   = (const float*)d_in[3];   // [2H,D1]
  const float* b1   = (const float*)d_in[4];   // [D1]
  const float* W2   = (const float*)d_in[5];   // [D1,1]
  const float* b2   = (const float*)d_in[6];   // [1]
  float* out = (float*)d_out;                  // [B]

  float* wsf = (float*)d_ws;
  float* cls = wsf;                            // [Bn][768]
  float* gp  = cls + (size_t)Bn * H;           // [2][Bn][768]
  float* P   = gp + (size_t)2 * Bn * H;        // [NC][Bn][D1]

  hipLaunchKernelGGL(pool_partial, dim3(Bn * 2), dim3(192), 0, stream,
                     feat, start, endp, cls, gp);
  hipLaunchKernelGGL(head_partial, dim3((Bn / E) * NC), dim3(256), 0, stream,
                     cls, gp, W1, P);
  hipLaunchKernelGGL(finalize, dim3(Bn / 4), dim3(256), 0, stream,
                     P, b1, W2, b2, out);
}